// Round 6
// baseline (309.479 us; speedup 1.0000x reference)
//
#include <hip/hip_runtime.h>
#include <hip/hip_bf16.h>

#define N_NODES 50000
#define N_EDGES 800000
#define D_IN 128
#define D_H 64
#define SCAN_BLOCKS 196   // ceil(50000/256)
#define HIST_BLOCKS 3125  // N_EDGES/256
#define LIN1_BLOCKS 782   // ceil(3125 waves / 4)
#define FRAG_BLOCKS 8     // 2048 frags for W2/W3 (W1 frags built in-LDS by lin1 blocks)
#define GL_BLOCKS 3125    // 16 nodes/block

// global W-frag table (layers 2/3 only), offsets in ushorts
#define F2L 0
#define F2R 4096
#define F3L 8192
#define F3R 12288
#define FRAG_TOTAL 16384  // 32 KB

typedef short bf16x8 __attribute__((ext_vector_type(8)));
typedef float f32x4 __attribute__((ext_vector_type(4)));

__device__ __forceinline__ ushort f2bf(float f) {
    __hip_bfloat16 b = __float2bfloat16(f);
    return *reinterpret_cast<ushort*>(&b);
}
__device__ __forceinline__ float bf16_lo(unsigned int u) { return __uint_as_float(u << 16); }
__device__ __forceinline__ float bf16_hi(unsigned int u) { return __uint_as_float(u & 0xffff0000u); }

// ---------- W-fragment build: frag[fid] = 16x16x32-bf16 B-fragment ----------
__device__ __forceinline__ void build_frag_kt(const float* __restrict__ W, int ktA, int nt,
                                              int lane, ushort* __restrict__ frag, int fid) {
    int quad = lane >> 4, col = lane & 15;
    ushort t0 = f2bf(W[(ktA * 32 + quad * 8 + 0) * D_H + nt * 16 + col]);
    ushort t1 = f2bf(W[(ktA * 32 + quad * 8 + 1) * D_H + nt * 16 + col]);
    ushort t2 = f2bf(W[(ktA * 32 + quad * 8 + 2) * D_H + nt * 16 + col]);
    ushort t3 = f2bf(W[(ktA * 32 + quad * 8 + 3) * D_H + nt * 16 + col]);
    ushort t4 = f2bf(W[(ktA * 32 + quad * 8 + 4) * D_H + nt * 16 + col]);
    ushort t5 = f2bf(W[(ktA * 32 + quad * 8 + 5) * D_H + nt * 16 + col]);
    ushort t6 = f2bf(W[(ktA * 32 + quad * 8 + 6) * D_H + nt * 16 + col]);
    ushort t7 = f2bf(W[(ktA * 32 + quad * 8 + 7) * D_H + nt * 16 + col]);
    uint4 v;
    v.x = (unsigned int)t0 | ((unsigned int)t1 << 16);
    v.y = (unsigned int)t2 | ((unsigned int)t3 << 16);
    v.z = (unsigned int)t4 | ((unsigned int)t5 << 16);
    v.w = (unsigned int)t6 | ((unsigned int)t7 << 16);
    *reinterpret_cast<uint4*>(frag + (size_t)fid * 8) = v;
}

__device__ __forceinline__ void build_frag_one(const float* __restrict__ W, int local,
                                               ushort* __restrict__ frag, int fid) {
    int lane = local & 63;
    int ktnt = local >> 6;
    build_frag_kt(W, ktnt >> 2, ktnt & 3, lane, frag, fid);
}

// ---------- K1: lin1 (16KB staged LDS frags) || frag build (W2/W3) || hist+rank ----------
__global__ void k1_kernel(const float* __restrict__ x,
                          const float* __restrict__ Wl1, const float* __restrict__ Wr1,
                          const float* __restrict__ Wl2, const float* __restrict__ Wr2,
                          const float* __restrict__ Wl3, const float* __restrict__ Wr3,
                          const int* __restrict__ dstv, int* __restrict__ cnt,
                          ushort* __restrict__ rank, ushort* __restrict__ wfrag,
                          ushort* __restrict__ Y, ushort* __restrict__ Zb) {
    __shared__ ushort fl[4096];  // 8 KB: W1-left frags, 2 kt at a time
    __shared__ ushort fr[4096];  // 8 KB: W1-right frags
    if (blockIdx.x < LIN1_BLOCKS) {
        int tid = threadIdx.x;
        int lane = tid & 63;
        int gwave = (blockIdx.x * 256 + tid) >> 6;
        int m0 = gwave * 16;
        int col = lane & 15;
        int quad = lane >> 4;
        f32x4 accl[4], accr[4];
#pragma unroll
        for (int nt = 0; nt < 4; ++nt) {
            accl[nt] = (f32x4){0.f, 0.f, 0.f, 0.f};
            accr[nt] = (f32x4){0.f, 0.f, 0.f, 0.f};
        }
        const float* arow = x + (size_t)(m0 + col) * D_IN + quad * 8;
#pragma unroll
        for (int s = 0; s < 2; ++s) {
#pragma unroll
            for (int i = 0; i < 2; ++i) {
                int local = i * 256 + tid;       // 0..511
                int ktnt = local >> 6;           // 0..7
                int kt_l = ktnt >> 2, nt = ktnt & 3;
                build_frag_kt(Wl1, 2 * s + kt_l, nt, local & 63, fl, local);
                build_frag_kt(Wr1, 2 * s + kt_l, nt, local & 63, fr, local);
            }
            __syncthreads();
            if (m0 < N_NODES) {
#pragma unroll
                for (int kt_l = 0; kt_l < 2; ++kt_l) {
                    int ktA = 2 * s + kt_l;
                    float4 a_lo = *reinterpret_cast<const float4*>(arow + ktA * 32);
                    float4 a_hi = *reinterpret_cast<const float4*>(arow + ktA * 32 + 4);
                    bf16x8 a;
                    a[0] = (short)f2bf(a_lo.x); a[1] = (short)f2bf(a_lo.y);
                    a[2] = (short)f2bf(a_lo.z); a[3] = (short)f2bf(a_lo.w);
                    a[4] = (short)f2bf(a_hi.x); a[5] = (short)f2bf(a_hi.y);
                    a[6] = (short)f2bf(a_hi.z); a[7] = (short)f2bf(a_hi.w);
#pragma unroll
                    for (int nt = 0; nt < 4; ++nt) {
                        size_t off = (size_t)((kt_l * 4 + nt) * 64 + lane) * 8;
                        bf16x8 bl = __builtin_bit_cast(bf16x8, *reinterpret_cast<const uint4*>(fl + off));
                        bf16x8 br = __builtin_bit_cast(bf16x8, *reinterpret_cast<const uint4*>(fr + off));
                        accl[nt] = __builtin_amdgcn_mfma_f32_16x16x32_bf16(a, bl, accl[nt], 0, 0, 0);
                        accr[nt] = __builtin_amdgcn_mfma_f32_16x16x32_bf16(a, br, accr[nt], 0, 0, 0);
                    }
                }
            }
            if (s == 0) __syncthreads();
        }
        if (m0 < N_NODES) {
#pragma unroll
            for (int reg = 0; reg < 4; ++reg) {
                size_t r = (size_t)(m0 + quad * 4 + reg) * D_H;
                ushort* yp = Y + r;
                ushort* zp = Zb + r;
#pragma unroll
                for (int nt = 0; nt < 4; ++nt) {
                    yp[nt * 16 + col] = f2bf(accl[nt][reg]);
                    zp[nt * 16 + col] = f2bf(accr[nt][reg]);
                }
            }
        }
    } else if (blockIdx.x < LIN1_BLOCKS + FRAG_BLOCKS) {
        int fid = (blockIdx.x - LIN1_BLOCKS) * 256 + threadIdx.x;  // 0..2047
        const float* W; int base;
        if (fid < 512)       { W = Wl2; base = 0; }
        else if (fid < 1024) { W = Wr2; base = 512; }
        else if (fid < 1536) { W = Wl3; base = 1024; }
        else                 { W = Wr3; base = 1536; }
        build_frag_one(W, fid - base, wfrag, fid);
    } else {
        int e = (blockIdx.x - LIN1_BLOCKS - FRAG_BLOCKS) * 256 + threadIdx.x;
        if (e < N_EDGES) {
            int r = atomicAdd(&cnt[dstv[e]], 1);
            rank[e] = (ushort)r;
        }
    }
}

// ---------- K2: per-block partial sums ----------
__global__ void scan_partial(const int* __restrict__ cnt, int* __restrict__ blockSums) {
    __shared__ int s[256];
    int i = blockIdx.x * 256 + threadIdx.x;
    s[threadIdx.x] = (i < N_NODES) ? cnt[i] : 0;
    __syncthreads();
    for (int off = 128; off > 0; off >>= 1) {
        if (threadIdx.x < off) s[threadIdx.x] += s[threadIdx.x + off];
        __syncthreads();
    }
    if (threadIdx.x == 0) blockSums[blockIdx.x] = s[0];
}

// ---------- K3: fused blockSums-scan + final scan ----------
__global__ void scan_final(const int* __restrict__ cnt, const int* __restrict__ blockSums,
                           int* __restrict__ row_ptr) {
    __shared__ int s[256];
    __shared__ int bs[256];
    int t = threadIdx.x;
    bs[t] = (t < SCAN_BLOCKS) ? blockSums[t] : 0;
    int i = blockIdx.x * 256 + t;
    s[t] = (i < N_NODES) ? cnt[i] : 0;
    __syncthreads();
    for (int off = 1; off < 256; off <<= 1) {
        int tmp1 = (t >= off) ? s[t - off] : 0;
        int tmp2 = (t >= off) ? bs[t - off] : 0;
        __syncthreads();
        s[t] += tmp1;
        bs[t] += tmp2;
        __syncthreads();
    }
    int blockExcl = (blockIdx.x > 0) ? bs[blockIdx.x - 1] : 0;
    int excl = blockExcl + ((t > 0) ? s[t - 1] : 0);
    if (i < N_NODES) row_ptr[i] = excl;
    if (i == 0) row_ptr[N_NODES] = N_EDGES;
}

// ---------- K4: rank-based CSR fill ----------
__global__ void fill_kernel(const int* __restrict__ srcv, const int* __restrict__ dstv,
                            const ushort* __restrict__ rank, const int* __restrict__ row_ptr,
                            ushort* __restrict__ csr_src) {
    int e = blockIdx.x * 256 + threadIdx.x;
    if (e < N_EDGES) {
        int d = dstv[e];
        int pos = row_ptr[d] + (int)rank[e];
        csr_src[pos] = (ushort)srcv[e];
    }
}

// ---------- MFMA-aggregation gather + fused next-layer lin / output proj ----------
// Block = 16 consecutive nodes -> contiguous CSR range [E0,E1). Super-chunks of 128
// edges: all 256 threads stage 128 src rows (Y, bf16 [128][72] padded) via uint4
// loads + ds_write_b128; each wave computes Sel(16x32) @ Rows(32x16) x 4 feat-tiles
// with mfma_f32_16x16x32_bf16. Sel built in registers (0/1 bf16, exact).
template <bool FUSE_PROJ>
__global__ void gather_lin_kernel(const ushort* __restrict__ Y, const ushort* __restrict__ Zb,
                                  const float* __restrict__ bl,
                                  const int* __restrict__ row_ptr, const ushort* __restrict__ csr_src,
                                  const ushort* __restrict__ fragWl, const ushort* __restrict__ fragWr,
                                  ushort* __restrict__ Ynext, ushort* __restrict__ Zbnext,
                                  const float* __restrict__ Wp, const float* __restrict__ bp,
                                  float* __restrict__ ps, float* __restrict__ pd) {
    __shared__ uint4 smemv[1152];      // 18.4 KB: He ushort[128][72] / aliased f32 Hred[4][16][68]
    __shared__ ushort Hs[16][72];
    __shared__ int rp_s[17];
    ushort* He = (ushort*)smemv;
    float* Hf = (float*)smemv;

    int tid = threadIdx.x;
    int w = tid >> 6;
    int lane = tid & 63;
    int q = lane >> 4;
    int cc = lane & 15;
    int n0base = blockIdx.x * 16;

    if (tid < 17) rp_s[tid] = row_ptr[n0base + tid];
    __syncthreads();
    int E0 = rp_s[0];
    int T = rp_s[16] - E0;
    int rlo = rp_s[cc];
    int rhi = rp_s[cc + 1];

    f32x4 acc[4];
#pragma unroll
    for (int nt = 0; nt < 4; ++nt) acc[nt] = (f32x4){0.f, 0.f, 0.f, 0.f};

    const uint4* __restrict__ Yv4 = reinterpret_cast<const uint4*>(Y);  // 8 uint4 per row

    for (int sc = 0; sc * 128 < T; ++sc) {
        // ---- stage 128 rows: issue all loads first (MLP), then LDS writes ----
        uint4 sv[4]; int dsidx[4];
#pragma unroll
        for (int it = 0; it < 4; ++it) {
            int m = it * 256 + tid;          // 0..1023
            int k = m >> 3;                  // edge slot 0..127
            int ch = m & 7;                  // 16B chunk within row
            int p = E0 + sc * 128 + k;       // csr pos (padded reads OK)
            int sid = (int)csr_src[p];
            sv[it] = Yv4[(size_t)sid * 8 + ch];
            dsidx[it] = k * 9 + ch;          // He row stride = 72 ushorts = 9 uint4
        }
        __syncthreads();                     // prev compute done before overwrite
#pragma unroll
        for (int it = 0; it < 4; ++it) smemv[dsidx[it]] = sv[it];
        __syncthreads();                     // staged data visible

        // ---- compute: wave w owns edges [sc*128 + w*32, +32) ----
        int ebase = sc * 128 + w * 32;
        if (ebase < T) {
            bf16x8 af;
#pragma unroll
            for (int i = 0; i < 8; ++i) {
                int p = E0 + ebase + q * 8 + i;
                af[i] = (short)((p >= rlo && p < rhi) ? 0x3F80 : 0);  // bf16 1.0 / 0.0
            }
#pragma unroll
            for (int nt = 0; nt < 4; ++nt) {
                bf16x8 bf_;
#pragma unroll
                for (int i = 0; i < 8; ++i) {
                    int k = w * 32 + q * 8 + i;
                    bf_[i] = (short)He[k * 72 + nt * 16 + cc];
                }
                acc[nt] = __builtin_amdgcn_mfma_f32_16x16x32_bf16(af, bf_, acc[nt], 0, 0, 0);
            }
        }
    }
    __syncthreads();   // all He reads done before Hred aliasing writes

    // ---- cross-wave reduction through LDS (Hred[w][node][68-padded feats]) ----
#pragma unroll
    for (int nt = 0; nt < 4; ++nt)
#pragma unroll
        for (int reg = 0; reg < 4; ++reg)
            Hf[w * 1088 + (q * 4 + reg) * 68 + nt * 16 + cc] = acc[nt][reg];
    __syncthreads();

    // ---- epilogue: thread t owns node n = t>>4, feats fq*4..+3 ----
    int n = tid >> 4;
    int fq = tid & 15;
    const float4* Hp = reinterpret_cast<const float4*>(Hf);
    float4 s0 = Hp[0 * 272 + n * 17 + fq];
    float4 s1 = Hp[1 * 272 + n * 17 + fq];
    float4 s2 = Hp[2 * 272 + n * 17 + fq];
    float4 s3 = Hp[3 * 272 + n * 17 + fq];
    float c0 = s0.x + s1.x + s2.x + s3.x;
    float c1 = s0.y + s1.y + s2.y + s3.y;
    float c2 = s0.z + s1.z + s2.z + s3.z;
    float c3 = s0.w + s1.w + s2.w + s3.w;

    int node = n0base + n;
    float dgf = (float)(rp_s[n + 1] - rp_s[n]);
    float inv = 1.0f / fmaxf(dgf, 1.0f);
    float4 bv = reinterpret_cast<const float4*>(bl)[fq];
    uint2 zr = reinterpret_cast<const uint2*>(Zb)[node * 16 + fq];
    float v0 = c0 * inv + bv.x + bf16_lo(zr.x);
    float v1 = c1 * inv + bv.y + bf16_hi(zr.x);
    float v2 = c2 * inv + bv.z + bf16_lo(zr.y);
    float v3 = c3 * inv + bv.w + bf16_hi(zr.y);
    float o0 = v0 > 0.f ? v0 : expm1f(v0);
    float o1 = v1 > 0.f ? v1 : expm1f(v1);
    float o2 = v2 > 0.f ? v2 : expm1f(v2);
    float o3 = v3 > 0.f ? v3 : expm1f(v3);

    if constexpr (FUSE_PROJ) {
        float p0 = 0.f, p1 = 0.f, p2 = 0.f, p3 = 0.f;
        float q0 = 0.f, q1 = 0.f, q2 = 0.f, q3 = 0.f;
        float ov[4] = {o0, o1, o2, o3};
#pragma unroll
        for (int j = 0; j < 4; ++j) {
            int k = 4 * fq + j;
            float4 wt = reinterpret_cast<const float4*>(Wp)[k];
            float4 wb = reinterpret_cast<const float4*>(Wp)[D_H + k];
            p0 += ov[j] * wt.x; p1 += ov[j] * wt.y; p2 += ov[j] * wt.z; p3 += ov[j] * wt.w;
            q0 += ov[j] * wb.x; q1 += ov[j] * wb.y; q2 += ov[j] * wb.z; q3 += ov[j] * wb.w;
        }
#pragma unroll
        for (int off = 1; off < 16; off <<= 1) {
            p0 += __shfl_xor(p0, off); p1 += __shfl_xor(p1, off);
            p2 += __shfl_xor(p2, off); p3 += __shfl_xor(p3, off);
            q0 += __shfl_xor(q0, off); q1 += __shfl_xor(q1, off);
            q2 += __shfl_xor(q2, off); q3 += __shfl_xor(q3, off);
        }
        if (fq == 0) {
            float4 bpv = *reinterpret_cast<const float4*>(bp);
            float4 pv; pv.x = p0 + bpv.x; pv.y = p1 + bpv.y; pv.z = p2 + bpv.z; pv.w = p3 + bpv.w;
            float4 qv; qv.x = q0; qv.y = q1; qv.z = q2; qv.w = q3;
            reinterpret_cast<float4*>(ps)[node] = pv;   // bp folded into ps
            reinterpret_cast<float4*>(pd)[node] = qv;
        }
    } else {
        ushort4 ob;
        ob.x = f2bf(o0); ob.y = f2bf(o1); ob.z = f2bf(o2); ob.w = f2bf(o3);
        *reinterpret_cast<ushort4*>(&Hs[n][4 * fq]) = ob;
        __syncthreads();

        int col = lane & 15;
        int quad = lane >> 4;
        bf16x8 blf0 = __builtin_bit_cast(bf16x8,
            *reinterpret_cast<const uint4*>(fragWl + (size_t)((0 * 4 + w) * 64 + lane) * 8));
        bf16x8 blf1 = __builtin_bit_cast(bf16x8,
            *reinterpret_cast<const uint4*>(fragWl + (size_t)((1 * 4 + w) * 64 + lane) * 8));
        bf16x8 brf0 = __builtin_bit_cast(bf16x8,
            *reinterpret_cast<const uint4*>(fragWr + (size_t)((0 * 4 + w) * 64 + lane) * 8));
        bf16x8 brf1 = __builtin_bit_cast(bf16x8,
            *reinterpret_cast<const uint4*>(fragWr + (size_t)((1 * 4 + w) * 64 + lane) * 8));
        bf16x8 a0 = __builtin_bit_cast(bf16x8,
            *reinterpret_cast<const uint4*>(&Hs[col][quad * 8]));
        bf16x8 a1 = __builtin_bit_cast(bf16x8,
            *reinterpret_cast<const uint4*>(&Hs[col][32 + quad * 8]));
        f32x4 accl = {0.f,0.f,0.f,0.f};
        f32x4 accr = {0.f,0.f,0.f,0.f};
        accl = __builtin_amdgcn_mfma_f32_16x16x32_bf16(a0, blf0, accl, 0, 0, 0);
        accl = __builtin_amdgcn_mfma_f32_16x16x32_bf16(a1, blf1, accl, 0, 0, 0);
        accr = __builtin_amdgcn_mfma_f32_16x16x32_bf16(a0, brf0, accr, 0, 0, 0);
        accr = __builtin_amdgcn_mfma_f32_16x16x32_bf16(a1, brf1, accr, 0, 0, 0);

#pragma unroll
        for (int reg = 0; reg < 4; ++reg) {
            size_t r = (size_t)(n0base + quad * 4 + reg) * D_H + w * 16 + col;
            Ynext[r]  = f2bf(accl[reg]);
            Zbnext[r] = f2bf(accr[reg]);
        }
    }
}

__global__ void edge_final_kernel(const int* __restrict__ srcv, const int* __restrict__ dstv,
                                  const float* __restrict__ ps, const float* __restrict__ pd,
                                  float* __restrict__ out) {
    int e = blockIdx.x * 256 + threadIdx.x;
    if (e >= N_EDGES) return;
    float4 a = reinterpret_cast<const float4*>(ps)[srcv[e]];  // already has +bp
    float4 b = reinterpret_cast<const float4*>(pd)[dstv[e]];
    float4 o;
    o.x = a.x + b.x;
    o.y = a.y + b.y;
    o.z = a.z + b.z;
    o.w = a.w + b.w;
    reinterpret_cast<float4*>(out)[e] = o;
}

extern "C" void kernel_launch(void* const* d_in, const int* in_sizes, int n_in,
                              void* d_out, int out_size, void* d_ws, size_t ws_size,
                              hipStream_t stream) {
    const float* x   = (const float*)d_in[0];
    const int*   ei  = (const int*)d_in[1];
    const float* Wl1 = (const float*)d_in[2];
    const float* bl1 = (const float*)d_in[3];
    const float* Wr1 = (const float*)d_in[4];
    const float* Wl2 = (const float*)d_in[5];
    const float* bl2 = (const float*)d_in[6];
    const float* Wr2 = (const float*)d_in[7];
    const float* Wl3 = (const float*)d_in[8];
    const float* bl3 = (const float*)d_in[9];
    const float* Wr3 = (const float*)d_in[10];
    const float* Wp  = (const float*)d_in[11];
    const float* bp  = (const float*)d_in[12];
    float* out = (float*)d_out;

    const int* srcv = ei;
    const int* dstv = ei + N_EDGES;

    // ---- workspace carve-up ----
    int*   cnt       = (int*)d_ws;                     // 50000
    int*   blockSums = cnt + 50000;                    // 256
    int*   row_ptr   = blockSums + 256;                // 50001
    ushort* rank     = (ushort*)(row_ptr + 50001);     // 800000
    ushort* csr_src  = rank + 800000;                  // 800000 (+4096 pad)
    ushort* wfrag = (ushort*)(((uintptr_t)(csr_src + 800000 + 4096) + 127) & ~(uintptr_t)127);
    ushort* Y1  = (ushort*)(((uintptr_t)(wfrag + FRAG_TOTAL) + 127) & ~(uintptr_t)127);
    ushort* Zb1 = Y1 + (size_t)N_NODES * D_H;
    ushort* Y2  = Zb1 + (size_t)N_NODES * D_H;
    ushort* Zb2 = Y2 + (size_t)N_NODES * D_H;
    float* ps = (float*)(((uintptr_t)(Zb2 + (size_t)N_NODES * D_H) + 15) & ~(uintptr_t)15);
    float* pd = ps + (size_t)N_NODES * 4;

    // ---- K1: lin1 (staged 16KB LDS frags) || frag build W2/W3 || hist+rank ----
    hipMemsetAsync(cnt, 0, N_NODES * sizeof(int), stream);
    k1_kernel<<<LIN1_BLOCKS + FRAG_BLOCKS + HIST_BLOCKS, 256, 0, stream>>>(
        x, Wl1, Wr1, Wl2, Wr2, Wl3, Wr3, dstv, cnt, rank, wfrag, Y1, Zb1);

    // ---- K2/K3: two-dispatch scan ----
    scan_partial<<<SCAN_BLOCKS, 256, 0, stream>>>(cnt, blockSums);
    scan_final<<<SCAN_BLOCKS, 256, 0, stream>>>(cnt, blockSums, row_ptr);

    // ---- K4: CSR fill ----
    fill_kernel<<<HIST_BLOCKS, 256, 0, stream>>>(srcv, dstv, rank, row_ptr, csr_src);

    // ---- K5: gather L1 + lin L2 ----
    gather_lin_kernel<false><<<GL_BLOCKS, 256, 0, stream>>>(Y1, Zb1, bl1, row_ptr, csr_src,
                                                            wfrag + F2L, wfrag + F2R, Y2, Zb2,
                                                            nullptr, nullptr, nullptr, nullptr);

    // ---- K6: gather L2 + lin L3 ----
    gather_lin_kernel<false><<<GL_BLOCKS, 256, 0, stream>>>(Y2, Zb2, bl2, row_ptr, csr_src,
                                                            wfrag + F3L, wfrag + F3R, Y1, Zb1,
                                                            nullptr, nullptr, nullptr, nullptr);

    // ---- K7: gather L3 + fused output projection (bp folded into ps) ----
    gather_lin_kernel<true><<<GL_BLOCKS, 256, 0, stream>>>(Y1, Zb1, bl3, row_ptr, csr_src,
                                                           nullptr, nullptr, nullptr, nullptr,
                                                           Wp, bp, ps, pd);

    // ---- K8: edge output ----
    edge_final_kernel<<<(N_EDGES + 255) / 256, 256, 0, stream>>>(srcv, dstv, ps, pd, out);
}

// Round 7
// 229.082 us; speedup vs baseline: 1.3510x; 1.3510x over previous
//
#include <hip/hip_runtime.h>
#include <hip/hip_bf16.h>

#define N_NODES 50000
#define N_EDGES 800000
#define D_IN 128
#define D_H 64
#define SCAN_BLOCKS 196   // ceil(50000/256)
#define HIST_BLOCKS 3125  // N_EDGES/256
#define LIN1_BLOCKS 782   // ceil(3125 waves / 4)
#define FRAG_BLOCKS 8     // 2048 frags for W2/W3 (W1 frags built in-LDS by lin1 blocks)
#define GL_BLOCKS 3125    // 16 nodes/block

// global W-frag table (layers 2/3 only), offsets in ushorts
#define F2L 0
#define F2R 4096
#define F3L 8192
#define F3R 12288
#define FRAG_TOTAL 16384  // 32 KB

typedef short bf16x8 __attribute__((ext_vector_type(8)));
typedef float f32x4 __attribute__((ext_vector_type(4)));

__device__ __forceinline__ ushort f2bf(float f) {
    __hip_bfloat16 b = __float2bfloat16(f);
    return *reinterpret_cast<ushort*>(&b);
}
__device__ __forceinline__ float bf16_lo(unsigned int u) { return __uint_as_float(u << 16); }
__device__ __forceinline__ float bf16_hi(unsigned int u) { return __uint_as_float(u & 0xffff0000u); }

// ---------- W-fragment build: frag[fid] = 16x16x32-bf16 B-fragment ----------
__device__ __forceinline__ void build_frag_kt(const float* __restrict__ W, int ktA, int nt,
                                              int lane, ushort* __restrict__ frag, int fid) {
    int quad = lane >> 4, col = lane & 15;
    ushort t0 = f2bf(W[(ktA * 32 + quad * 8 + 0) * D_H + nt * 16 + col]);
    ushort t1 = f2bf(W[(ktA * 32 + quad * 8 + 1) * D_H + nt * 16 + col]);
    ushort t2 = f2bf(W[(ktA * 32 + quad * 8 + 2) * D_H + nt * 16 + col]);
    ushort t3 = f2bf(W[(ktA * 32 + quad * 8 + 3) * D_H + nt * 16 + col]);
    ushort t4 = f2bf(W[(ktA * 32 + quad * 8 + 4) * D_H + nt * 16 + col]);
    ushort t5 = f2bf(W[(ktA * 32 + quad * 8 + 5) * D_H + nt * 16 + col]);
    ushort t6 = f2bf(W[(ktA * 32 + quad * 8 + 6) * D_H + nt * 16 + col]);
    ushort t7 = f2bf(W[(ktA * 32 + quad * 8 + 7) * D_H + nt * 16 + col]);
    uint4 v;
    v.x = (unsigned int)t0 | ((unsigned int)t1 << 16);
    v.y = (unsigned int)t2 | ((unsigned int)t3 << 16);
    v.z = (unsigned int)t4 | ((unsigned int)t5 << 16);
    v.w = (unsigned int)t6 | ((unsigned int)t7 << 16);
    *reinterpret_cast<uint4*>(frag + (size_t)fid * 8) = v;
}

__device__ __forceinline__ void build_frag_one(const float* __restrict__ W, int local,
                                               ushort* __restrict__ frag, int fid) {
    int lane = local & 63;
    int ktnt = local >> 6;
    build_frag_kt(W, ktnt >> 2, ktnt & 3, lane, frag, fid);
}

// ---------- K1: lin1 (16KB staged LDS frags) || frag build (W2/W3) || hist+rank ----------
__global__ void k1_kernel(const float* __restrict__ x,
                          const float* __restrict__ Wl1, const float* __restrict__ Wr1,
                          const float* __restrict__ Wl2, const float* __restrict__ Wr2,
                          const float* __restrict__ Wl3, const float* __restrict__ Wr3,
                          const int* __restrict__ dstv, int* __restrict__ cnt,
                          ushort* __restrict__ rank, ushort* __restrict__ wfrag,
                          ushort* __restrict__ Y, ushort* __restrict__ Zb) {
    __shared__ ushort fl[4096];  // 8 KB: W1-left frags, 2 kt at a time
    __shared__ ushort fr[4096];  // 8 KB: W1-right frags
    if (blockIdx.x < LIN1_BLOCKS) {
        int tid = threadIdx.x;
        int lane = tid & 63;
        int gwave = (blockIdx.x * 256 + tid) >> 6;
        int m0 = gwave * 16;
        int col = lane & 15;
        int quad = lane >> 4;
        f32x4 accl[4], accr[4];
#pragma unroll
        for (int nt = 0; nt < 4; ++nt) {
            accl[nt] = (f32x4){0.f, 0.f, 0.f, 0.f};
            accr[nt] = (f32x4){0.f, 0.f, 0.f, 0.f};
        }
        const float* arow = x + (size_t)(m0 + col) * D_IN + quad * 8;
#pragma unroll
        for (int s = 0; s < 2; ++s) {
#pragma unroll
            for (int i = 0; i < 2; ++i) {
                int local = i * 256 + tid;       // 0..511
                int ktnt = local >> 6;           // 0..7
                int kt_l = ktnt >> 2, nt = ktnt & 3;
                build_frag_kt(Wl1, 2 * s + kt_l, nt, local & 63, fl, local);
                build_frag_kt(Wr1, 2 * s + kt_l, nt, local & 63, fr, local);
            }
            __syncthreads();
            if (m0 < N_NODES) {
#pragma unroll
                for (int kt_l = 0; kt_l < 2; ++kt_l) {
                    int ktA = 2 * s + kt_l;
                    float4 a_lo = *reinterpret_cast<const float4*>(arow + ktA * 32);
                    float4 a_hi = *reinterpret_cast<const float4*>(arow + ktA * 32 + 4);
                    bf16x8 a;
                    a[0] = (short)f2bf(a_lo.x); a[1] = (short)f2bf(a_lo.y);
                    a[2] = (short)f2bf(a_lo.z); a[3] = (short)f2bf(a_lo.w);
                    a[4] = (short)f2bf(a_hi.x); a[5] = (short)f2bf(a_hi.y);
                    a[6] = (short)f2bf(a_hi.z); a[7] = (short)f2bf(a_hi.w);
#pragma unroll
                    for (int nt = 0; nt < 4; ++nt) {
                        size_t off = (size_t)((kt_l * 4 + nt) * 64 + lane) * 8;
                        bf16x8 bl = __builtin_bit_cast(bf16x8, *reinterpret_cast<const uint4*>(fl + off));
                        bf16x8 br = __builtin_bit_cast(bf16x8, *reinterpret_cast<const uint4*>(fr + off));
                        accl[nt] = __builtin_amdgcn_mfma_f32_16x16x32_bf16(a, bl, accl[nt], 0, 0, 0);
                        accr[nt] = __builtin_amdgcn_mfma_f32_16x16x32_bf16(a, br, accr[nt], 0, 0, 0);
                    }
                }
            }
            if (s == 0) __syncthreads();
        }
        if (m0 < N_NODES) {
#pragma unroll
            for (int reg = 0; reg < 4; ++reg) {
                size_t r = (size_t)(m0 + quad * 4 + reg) * D_H;
                ushort* yp = Y + r;
                ushort* zp = Zb + r;
#pragma unroll
                for (int nt = 0; nt < 4; ++nt) {
                    yp[nt * 16 + col] = f2bf(accl[nt][reg]);
                    zp[nt * 16 + col] = f2bf(accr[nt][reg]);
                }
            }
        }
    } else if (blockIdx.x < LIN1_BLOCKS + FRAG_BLOCKS) {
        int fid = (blockIdx.x - LIN1_BLOCKS) * 256 + threadIdx.x;  // 0..2047
        const float* W; int base;
        if (fid < 512)       { W = Wl2; base = 0; }
        else if (fid < 1024) { W = Wr2; base = 512; }
        else if (fid < 1536) { W = Wl3; base = 1024; }
        else                 { W = Wr3; base = 1536; }
        build_frag_one(W, fid - base, wfrag, fid);
    } else {
        int e = (blockIdx.x - LIN1_BLOCKS - FRAG_BLOCKS) * 256 + threadIdx.x;
        if (e < N_EDGES) {
            int r = atomicAdd(&cnt[dstv[e]], 1);
            rank[e] = (ushort)r;
        }
    }
}

// ---------- K2: per-block partial sums ----------
__global__ void scan_partial(const int* __restrict__ cnt, int* __restrict__ blockSums) {
    __shared__ int s[256];
    int i = blockIdx.x * 256 + threadIdx.x;
    s[threadIdx.x] = (i < N_NODES) ? cnt[i] : 0;
    __syncthreads();
    for (int off = 128; off > 0; off >>= 1) {
        if (threadIdx.x < off) s[threadIdx.x] += s[threadIdx.x + off];
        __syncthreads();
    }
    if (threadIdx.x == 0) blockSums[blockIdx.x] = s[0];
}

// ---------- K3: fused blockSums-scan + final scan ----------
__global__ void scan_final(const int* __restrict__ cnt, const int* __restrict__ blockSums,
                           int* __restrict__ row_ptr) {
    __shared__ int s[256];
    __shared__ int bs[256];
    int t = threadIdx.x;
    bs[t] = (t < SCAN_BLOCKS) ? blockSums[t] : 0;
    int i = blockIdx.x * 256 + t;
    s[t] = (i < N_NODES) ? cnt[i] : 0;
    __syncthreads();
    for (int off = 1; off < 256; off <<= 1) {
        int tmp1 = (t >= off) ? s[t - off] : 0;
        int tmp2 = (t >= off) ? bs[t - off] : 0;
        __syncthreads();
        s[t] += tmp1;
        bs[t] += tmp2;
        __syncthreads();
    }
    int blockExcl = (blockIdx.x > 0) ? bs[blockIdx.x - 1] : 0;
    int excl = blockExcl + ((t > 0) ? s[t - 1] : 0);
    if (i < N_NODES) row_ptr[i] = excl;
    if (i == 0) row_ptr[N_NODES] = N_EDGES;
}

// ---------- K4: rank-based CSR fill ----------
__global__ void fill_kernel(const int* __restrict__ srcv, const int* __restrict__ dstv,
                            const ushort* __restrict__ rank, const int* __restrict__ row_ptr,
                            ushort* __restrict__ csr_src) {
    int e = blockIdx.x * 256 + threadIdx.x;
    if (e < N_EDGES) {
        int d = dstv[e];
        int pos = row_ptr[d] + (int)rank[e];
        csr_src[pos] = (ushort)srcv[e];
    }
}

// ---------- fused gather(+ELU) then next-layer linYZ through LDS ----------
// gather phase: group g (16 lanes) covers feature chunk l of edges k+4j+g;
// 16 UNCONDITIONAL row loads in flight per iteration; branchless mask-fmac accumulate
// (garbage slots multiply finite bf16 data by 0.0 — safe, no exec-mask toggles).
template <bool FUSE_PROJ>
__global__ void gather_lin_kernel(const ushort* __restrict__ Y, const ushort* __restrict__ Zb,
                                  const float* __restrict__ bl,
                                  const int* __restrict__ row_ptr, const ushort* __restrict__ csr_src,
                                  const ushort* __restrict__ fragWl, const ushort* __restrict__ fragWr,
                                  ushort* __restrict__ Ynext, ushort* __restrict__ Zbnext,
                                  const float* __restrict__ Wp, const float* __restrict__ bp,
                                  float* __restrict__ ps, float* __restrict__ pd) {
    __shared__ ushort Hs[16][72];
    int w = threadIdx.x >> 6;
    int lane = threadIdx.x & 63;
    int wv = (blockIdx.x << 2) + w;
    int n0 = wv << 2;
    int g = lane >> 4;
    int l = lane & 15;

    int rp[5];
#pragma unroll
    for (int i = 0; i < 5; ++i) rp[i] = row_ptr[n0 + i];
    int deg[4];
#pragma unroll
    for (int n = 0; n < 4; ++n) deg[n] = rp[n + 1] - rp[n];
    int maxdeg = deg[0];
#pragma unroll
    for (int n = 1; n < 4; ++n) maxdeg = deg[n] > maxdeg ? deg[n] : maxdeg;

    float acc[4][4] = {{0.f}};
    const uint2* __restrict__ Y2 = reinterpret_cast<const uint2*>(Y);

    for (int base = 0; base < maxdeg; base += 64) {
        int idxv[4];
#pragma unroll
        for (int n = 0; n < 4; ++n) idxv[n] = (int)csr_src[rp[n] + base + lane]; // padded
        int wend[4];
#pragma unroll
        for (int n = 0; n < 4; ++n) { wend[n] = deg[n] - base; if (wend[n] > 64) wend[n] = 64; }
        int kmax = wend[0];
#pragma unroll
        for (int n = 1; n < 4; ++n) kmax = wend[n] > kmax ? wend[n] : kmax;
        for (int k = 0; k < kmax; k += 16) {
            uint2 rr[4][4];
#pragma unroll
            for (int n = 0; n < 4; ++n)
#pragma unroll
                for (int j = 0; j < 4; ++j) {
                    int s = __shfl(idxv[n], k + 4 * j + g);
                    rr[n][j] = Y2[s * 16 + l];
                }
#pragma unroll
            for (int n = 0; n < 4; ++n)
#pragma unroll
                for (int j = 0; j < 4; ++j) {
                    float m = (k + 4 * j + g < wend[n]) ? 1.0f : 0.0f;
                    acc[n][0] = fmaf(m, bf16_lo(rr[n][j].x), acc[n][0]);
                    acc[n][1] = fmaf(m, bf16_hi(rr[n][j].x), acc[n][1]);
                    acc[n][2] = fmaf(m, bf16_lo(rr[n][j].y), acc[n][2]);
                    acc[n][3] = fmaf(m, bf16_hi(rr[n][j].y), acc[n][3]);
                }
        }
    }

    // hoist epilogue operand loads before the reduction (overlap latency)
    int node = n0 + g;
    float4 bv = reinterpret_cast<const float4*>(bl)[l];
    uint2 zr = reinterpret_cast<const uint2*>(Zb)[node * 16 + l];

#pragma unroll
    for (int n = 0; n < 4; ++n)
#pragma unroll
        for (int f = 0; f < 4; ++f) {
            acc[n][f] += __shfl_xor(acc[n][f], 16);
            acc[n][f] += __shfl_xor(acc[n][f], 32);
        }

    // epilogue: group g owns node n0+g
    float dgf = (g == 0) ? (float)deg[0] : (g == 1) ? (float)deg[1]
              : (g == 2) ? (float)deg[2] : (float)deg[3];
    float c0 = (g == 0) ? acc[0][0] : (g == 1) ? acc[1][0] : (g == 2) ? acc[2][0] : acc[3][0];
    float c1 = (g == 0) ? acc[0][1] : (g == 1) ? acc[1][1] : (g == 2) ? acc[2][1] : acc[3][1];
    float c2 = (g == 0) ? acc[0][2] : (g == 1) ? acc[1][2] : (g == 2) ? acc[2][2] : acc[3][2];
    float c3 = (g == 0) ? acc[0][3] : (g == 1) ? acc[1][3] : (g == 2) ? acc[2][3] : acc[3][3];
    float inv = 1.0f / fmaxf(dgf, 1.0f);
    float v0 = c0 * inv + bv.x + bf16_lo(zr.x);
    float v1 = c1 * inv + bv.y + bf16_hi(zr.x);
    float v2 = c2 * inv + bv.z + bf16_lo(zr.y);
    float v3 = c3 * inv + bv.w + bf16_hi(zr.y);
    float o0 = v0 > 0.f ? v0 : expm1f(v0);
    float o1 = v1 > 0.f ? v1 : expm1f(v1);
    float o2 = v2 > 0.f ? v2 : expm1f(v2);
    float o3 = v3 > 0.f ? v3 : expm1f(v3);

    if constexpr (FUSE_PROJ) {
        float p0 = 0.f, p1 = 0.f, p2 = 0.f, p3 = 0.f;
        float q0 = 0.f, q1 = 0.f, q2 = 0.f, q3 = 0.f;
        float ov[4] = {o0, o1, o2, o3};
#pragma unroll
        for (int j = 0; j < 4; ++j) {
            int k = 4 * l + j;
            float4 wt = reinterpret_cast<const float4*>(Wp)[k];
            float4 wb = reinterpret_cast<const float4*>(Wp)[D_H + k];
            p0 += ov[j] * wt.x; p1 += ov[j] * wt.y; p2 += ov[j] * wt.z; p3 += ov[j] * wt.w;
            q0 += ov[j] * wb.x; q1 += ov[j] * wb.y; q2 += ov[j] * wb.z; q3 += ov[j] * wb.w;
        }
#pragma unroll
        for (int off = 1; off < 16; off <<= 1) {
            p0 += __shfl_xor(p0, off); p1 += __shfl_xor(p1, off);
            p2 += __shfl_xor(p2, off); p3 += __shfl_xor(p3, off);
            q0 += __shfl_xor(q0, off); q1 += __shfl_xor(q1, off);
            q2 += __shfl_xor(q2, off); q3 += __shfl_xor(q3, off);
        }
        if (l == 0) {
            float4 bpv = *reinterpret_cast<const float4*>(bp);
            float4 pv; pv.x = p0 + bpv.x; pv.y = p1 + bpv.y; pv.z = p2 + bpv.z; pv.w = p3 + bpv.w;
            float4 qv; qv.x = q0; qv.y = q1; qv.z = q2; qv.w = q3;
            reinterpret_cast<float4*>(ps)[node] = pv;   // bp folded into ps
            reinterpret_cast<float4*>(pd)[node] = qv;
        }
    } else {
        ushort4 ob;
        ob.x = f2bf(o0); ob.y = f2bf(o1); ob.z = f2bf(o2); ob.w = f2bf(o3);
        int localrow = w * 4 + g;
        *reinterpret_cast<ushort4*>(&Hs[localrow][4 * l]) = ob;
        __syncthreads();

        int col = lane & 15;
        int quad = lane >> 4;
        bf16x8 blf0 = __builtin_bit_cast(bf16x8,
            *reinterpret_cast<const uint4*>(fragWl + (size_t)((0 * 4 + w) * 64 + lane) * 8));
        bf16x8 blf1 = __builtin_bit_cast(bf16x8,
            *reinterpret_cast<const uint4*>(fragWl + (size_t)((1 * 4 + w) * 64 + lane) * 8));
        bf16x8 brf0 = __builtin_bit_cast(bf16x8,
            *reinterpret_cast<const uint4*>(fragWr + (size_t)((0 * 4 + w) * 64 + lane) * 8));
        bf16x8 brf1 = __builtin_bit_cast(bf16x8,
            *reinterpret_cast<const uint4*>(fragWr + (size_t)((1 * 4 + w) * 64 + lane) * 8));
        bf16x8 a0 = __builtin_bit_cast(bf16x8,
            *reinterpret_cast<const uint4*>(&Hs[col][quad * 8]));
        bf16x8 a1 = __builtin_bit_cast(bf16x8,
            *reinterpret_cast<const uint4*>(&Hs[col][32 + quad * 8]));
        f32x4 accl = {0.f,0.f,0.f,0.f};
        f32x4 accr = {0.f,0.f,0.f,0.f};
        accl = __builtin_amdgcn_mfma_f32_16x16x32_bf16(a0, blf0, accl, 0, 0, 0);
        accl = __builtin_amdgcn_mfma_f32_16x16x32_bf16(a1, blf1, accl, 0, 0, 0);
        accr = __builtin_amdgcn_mfma_f32_16x16x32_bf16(a0, brf0, accr, 0, 0, 0);
        accr = __builtin_amdgcn_mfma_f32_16x16x32_bf16(a1, brf1, accr, 0, 0, 0);

        int n0base = blockIdx.x * 16;
#pragma unroll
        for (int reg = 0; reg < 4; ++reg) {
            size_t r = (size_t)(n0base + quad * 4 + reg) * D_H + w * 16 + col;
            Ynext[r]  = f2bf(accl[reg]);
            Zbnext[r] = f2bf(accr[reg]);
        }
    }
}

__global__ void edge_final_kernel(const int* __restrict__ srcv, const int* __restrict__ dstv,
                                  const float* __restrict__ ps, const float* __restrict__ pd,
                                  float* __restrict__ out) {
    int e = blockIdx.x * 256 + threadIdx.x;
    if (e >= N_EDGES) return;
    float4 a = reinterpret_cast<const float4*>(ps)[srcv[e]];  // already has +bp
    float4 b = reinterpret_cast<const float4*>(pd)[dstv[e]];
    float4 o;
    o.x = a.x + b.x;
    o.y = a.y + b.y;
    o.z = a.z + b.z;
    o.w = a.w + b.w;
    reinterpret_cast<float4*>(out)[e] = o;
}

extern "C" void kernel_launch(void* const* d_in, const int* in_sizes, int n_in,
                              void* d_out, int out_size, void* d_ws, size_t ws_size,
                              hipStream_t stream) {
    const float* x   = (const float*)d_in[0];
    const int*   ei  = (const int*)d_in[1];
    const float* Wl1 = (const float*)d_in[2];
    const float* bl1 = (const float*)d_in[3];
    const float* Wr1 = (const float*)d_in[4];
    const float* Wl2 = (const float*)d_in[5];
    const float* bl2 = (const float*)d_in[6];
    const float* Wr2 = (const float*)d_in[7];
    const float* Wl3 = (const float*)d_in[8];
    const float* bl3 = (const float*)d_in[9];
    const float* Wr3 = (const float*)d_in[10];
    const float* Wp  = (const float*)d_in[11];
    const float* bp  = (const float*)d_in[12];
    float* out = (float*)d_out;

    const int* srcv = ei;
    const int* dstv = ei + N_EDGES;

    // ---- workspace carve-up ----
    int*   cnt       = (int*)d_ws;                     // 50000
    int*   blockSums = cnt + 50000;                    // 256
    int*   row_ptr   = blockSums + 256;                // 50001
    ushort* rank     = (ushort*)(row_ptr + 50001);     // 800000
    ushort* csr_src  = rank + 800000;                  // 800000 (+4096 pad)
    ushort* wfrag = (ushort*)(((uintptr_t)(csr_src + 800000 + 4096) + 127) & ~(uintptr_t)127);
    ushort* Y1  = (ushort*)(((uintptr_t)(wfrag + FRAG_TOTAL) + 127) & ~(uintptr_t)127);
    ushort* Zb1 = Y1 + (size_t)N_NODES * D_H;
    ushort* Y2  = Zb1 + (size_t)N_NODES * D_H;
    ushort* Zb2 = Y2 + (size_t)N_NODES * D_H;
    float* ps = (float*)(((uintptr_t)(Zb2 + (size_t)N_NODES * D_H) + 15) & ~(uintptr_t)15);
    float* pd = ps + (size_t)N_NODES * 4;

    // ---- K1: lin1 (staged 16KB LDS frags) || frag build W2/W3 || hist+rank ----
    hipMemsetAsync(cnt, 0, N_NODES * sizeof(int), stream);
    k1_kernel<<<LIN1_BLOCKS + FRAG_BLOCKS + HIST_BLOCKS, 256, 0, stream>>>(
        x, Wl1, Wr1, Wl2, Wr2, Wl3, Wr3, dstv, cnt, rank, wfrag, Y1, Zb1);

    // ---- K2/K3: two-dispatch scan ----
    scan_partial<<<SCAN_BLOCKS, 256, 0, stream>>>(cnt, blockSums);
    scan_final<<<SCAN_BLOCKS, 256, 0, stream>>>(cnt, blockSums, row_ptr);

    // ---- K4: CSR fill ----
    fill_kernel<<<HIST_BLOCKS, 256, 0, stream>>>(srcv, dstv, rank, row_ptr, csr_src);

    // ---- K5: gather L1 + lin L2 ----
    gather_lin_kernel<false><<<GL_BLOCKS, 256, 0, stream>>>(Y1, Zb1, bl1, row_ptr, csr_src,
                                                            wfrag + F2L, wfrag + F2R, Y2, Zb2,
                                                            nullptr, nullptr, nullptr, nullptr);

    // ---- K6: gather L2 + lin L3 ----
    gather_lin_kernel<false><<<GL_BLOCKS, 256, 0, stream>>>(Y2, Zb2, bl2, row_ptr, csr_src,
                                                            wfrag + F3L, wfrag + F3R, Y1, Zb1,
                                                            nullptr, nullptr, nullptr, nullptr);

    // ---- K7: gather L3 + fused output projection (bp folded into ps) ----
    gather_lin_kernel<true><<<GL_BLOCKS, 256, 0, stream>>>(Y1, Zb1, bl3, row_ptr, csr_src,
                                                           nullptr, nullptr, nullptr, nullptr,
                                                           Wp, bp, ps, pd);

    // ---- K8: edge output ----
    edge_final_kernel<<<(N_EDGES + 255) / 256, 256, 0, stream>>>(srcv, dstv, ps, pd, out);
}

// Round 8
// 228.403 us; speedup vs baseline: 1.3550x; 1.0030x over previous
//
#include <hip/hip_runtime.h>
#include <hip/hip_bf16.h>

#define N_NODES 50000
#define N_EDGES 800000
#define D_IN 128
#define D_H 64
#define SCAN_BLOCKS 196   // ceil(50000/256)
#define HIST_BLOCKS 3125  // N_EDGES/256
#define LIN1_BLOCKS 782   // ceil(3125 waves / 4)
#define FRAG_BLOCKS 8     // 2048 frags for W2/W3 (W1 frags built in-LDS by lin1 blocks)
#define GL_BLOCKS 3125    // 16 nodes/block

// global W-frag table (layers 2/3 only), offsets in ushorts
#define F2L 0
#define F2R 4096
#define F3L 8192
#define F3R 12288
#define FRAG_TOTAL 16384  // 32 KB

typedef short bf16x8 __attribute__((ext_vector_type(8)));
typedef float f32x4 __attribute__((ext_vector_type(4)));

__device__ __forceinline__ ushort f2bf(float f) {
    __hip_bfloat16 b = __float2bfloat16(f);
    return *reinterpret_cast<ushort*>(&b);
}
__device__ __forceinline__ float bf16_lo(unsigned int u) { return __uint_as_float(u << 16); }
__device__ __forceinline__ float bf16_hi(unsigned int u) { return __uint_as_float(u & 0xffff0000u); }

// ---------- W-fragment build: frag[fid] = 16x16x32-bf16 B-fragment ----------
__device__ __forceinline__ void build_frag_kt(const float* __restrict__ W, int ktA, int nt,
                                              int lane, ushort* __restrict__ frag, int fid) {
    int quad = lane >> 4, col = lane & 15;
    ushort t0 = f2bf(W[(ktA * 32 + quad * 8 + 0) * D_H + nt * 16 + col]);
    ushort t1 = f2bf(W[(ktA * 32 + quad * 8 + 1) * D_H + nt * 16 + col]);
    ushort t2 = f2bf(W[(ktA * 32 + quad * 8 + 2) * D_H + nt * 16 + col]);
    ushort t3 = f2bf(W[(ktA * 32 + quad * 8 + 3) * D_H + nt * 16 + col]);
    ushort t4 = f2bf(W[(ktA * 32 + quad * 8 + 4) * D_H + nt * 16 + col]);
    ushort t5 = f2bf(W[(ktA * 32 + quad * 8 + 5) * D_H + nt * 16 + col]);
    ushort t6 = f2bf(W[(ktA * 32 + quad * 8 + 6) * D_H + nt * 16 + col]);
    ushort t7 = f2bf(W[(ktA * 32 + quad * 8 + 7) * D_H + nt * 16 + col]);
    uint4 v;
    v.x = (unsigned int)t0 | ((unsigned int)t1 << 16);
    v.y = (unsigned int)t2 | ((unsigned int)t3 << 16);
    v.z = (unsigned int)t4 | ((unsigned int)t5 << 16);
    v.w = (unsigned int)t6 | ((unsigned int)t7 << 16);
    *reinterpret_cast<uint4*>(frag + (size_t)fid * 8) = v;
}

__device__ __forceinline__ void build_frag_one(const float* __restrict__ W, int local,
                                               ushort* __restrict__ frag, int fid) {
    int lane = local & 63;
    int ktnt = local >> 6;
    build_frag_kt(W, ktnt >> 2, ktnt & 3, lane, frag, fid);
}

// ---------- K1: lin1 (16KB staged LDS frags) || frag build (W2/W3) || hist+rank ----------
__global__ void k1_kernel(const float* __restrict__ x,
                          const float* __restrict__ Wl1, const float* __restrict__ Wr1,
                          const float* __restrict__ Wl2, const float* __restrict__ Wr2,
                          const float* __restrict__ Wl3, const float* __restrict__ Wr3,
                          const int* __restrict__ dstv, int* __restrict__ cnt,
                          ushort* __restrict__ rank, ushort* __restrict__ wfrag,
                          ushort* __restrict__ Y, ushort* __restrict__ Zb) {
    __shared__ ushort fl[4096];  // 8 KB: W1-left frags, 2 kt at a time
    __shared__ ushort fr[4096];  // 8 KB: W1-right frags
    if (blockIdx.x < LIN1_BLOCKS) {
        int tid = threadIdx.x;
        int lane = tid & 63;
        int gwave = (blockIdx.x * 256 + tid) >> 6;
        int m0 = gwave * 16;
        int col = lane & 15;
        int quad = lane >> 4;
        f32x4 accl[4], accr[4];
#pragma unroll
        for (int nt = 0; nt < 4; ++nt) {
            accl[nt] = (f32x4){0.f, 0.f, 0.f, 0.f};
            accr[nt] = (f32x4){0.f, 0.f, 0.f, 0.f};
        }
        const float* arow = x + (size_t)(m0 + col) * D_IN + quad * 8;
#pragma unroll
        for (int s = 0; s < 2; ++s) {
#pragma unroll
            for (int i = 0; i < 2; ++i) {
                int local = i * 256 + tid;       // 0..511
                int ktnt = local >> 6;           // 0..7
                int kt_l = ktnt >> 2, nt = ktnt & 3;
                build_frag_kt(Wl1, 2 * s + kt_l, nt, local & 63, fl, local);
                build_frag_kt(Wr1, 2 * s + kt_l, nt, local & 63, fr, local);
            }
            __syncthreads();
            if (m0 < N_NODES) {
#pragma unroll
                for (int kt_l = 0; kt_l < 2; ++kt_l) {
                    int ktA = 2 * s + kt_l;
                    float4 a_lo = *reinterpret_cast<const float4*>(arow + ktA * 32);
                    float4 a_hi = *reinterpret_cast<const float4*>(arow + ktA * 32 + 4);
                    bf16x8 a;
                    a[0] = (short)f2bf(a_lo.x); a[1] = (short)f2bf(a_lo.y);
                    a[2] = (short)f2bf(a_lo.z); a[3] = (short)f2bf(a_lo.w);
                    a[4] = (short)f2bf(a_hi.x); a[5] = (short)f2bf(a_hi.y);
                    a[6] = (short)f2bf(a_hi.z); a[7] = (short)f2bf(a_hi.w);
#pragma unroll
                    for (int nt = 0; nt < 4; ++nt) {
                        size_t off = (size_t)((kt_l * 4 + nt) * 64 + lane) * 8;
                        bf16x8 bl = __builtin_bit_cast(bf16x8, *reinterpret_cast<const uint4*>(fl + off));
                        bf16x8 br = __builtin_bit_cast(bf16x8, *reinterpret_cast<const uint4*>(fr + off));
                        accl[nt] = __builtin_amdgcn_mfma_f32_16x16x32_bf16(a, bl, accl[nt], 0, 0, 0);
                        accr[nt] = __builtin_amdgcn_mfma_f32_16x16x32_bf16(a, br, accr[nt], 0, 0, 0);
                    }
                }
            }
            if (s == 0) __syncthreads();
        }
        if (m0 < N_NODES) {
#pragma unroll
            for (int reg = 0; reg < 4; ++reg) {
                size_t r = (size_t)(m0 + quad * 4 + reg) * D_H;
                ushort* yp = Y + r;
                ushort* zp = Zb + r;
#pragma unroll
                for (int nt = 0; nt < 4; ++nt) {
                    yp[nt * 16 + col] = f2bf(accl[nt][reg]);
                    zp[nt * 16 + col] = f2bf(accr[nt][reg]);
                }
            }
        }
    } else if (blockIdx.x < LIN1_BLOCKS + FRAG_BLOCKS) {
        int fid = (blockIdx.x - LIN1_BLOCKS) * 256 + threadIdx.x;  // 0..2047
        const float* W; int base;
        if (fid < 512)       { W = Wl2; base = 0; }
        else if (fid < 1024) { W = Wr2; base = 512; }
        else if (fid < 1536) { W = Wl3; base = 1024; }
        else                 { W = Wr3; base = 1536; }
        build_frag_one(W, fid - base, wfrag, fid);
    } else {
        int e = (blockIdx.x - LIN1_BLOCKS - FRAG_BLOCKS) * 256 + threadIdx.x;
        if (e < N_EDGES) {
            int r = atomicAdd(&cnt[dstv[e]], 1);
            rank[e] = (ushort)r;
        }
    }
}

// ---------- K2: per-block partial sums ----------
__global__ void scan_partial(const int* __restrict__ cnt, int* __restrict__ blockSums) {
    __shared__ int s[256];
    int i = blockIdx.x * 256 + threadIdx.x;
    s[threadIdx.x] = (i < N_NODES) ? cnt[i] : 0;
    __syncthreads();
    for (int off = 128; off > 0; off >>= 1) {
        if (threadIdx.x < off) s[threadIdx.x] += s[threadIdx.x + off];
        __syncthreads();
    }
    if (threadIdx.x == 0) blockSums[blockIdx.x] = s[0];
}

// ---------- K3: fused blockSums-scan + final scan ----------
__global__ void scan_final(const int* __restrict__ cnt, const int* __restrict__ blockSums,
                           int* __restrict__ row_ptr) {
    __shared__ int s[256];
    __shared__ int bs[256];
    int t = threadIdx.x;
    bs[t] = (t < SCAN_BLOCKS) ? blockSums[t] : 0;
    int i = blockIdx.x * 256 + t;
    s[t] = (i < N_NODES) ? cnt[i] : 0;
    __syncthreads();
    for (int off = 1; off < 256; off <<= 1) {
        int tmp1 = (t >= off) ? s[t - off] : 0;
        int tmp2 = (t >= off) ? bs[t - off] : 0;
        __syncthreads();
        s[t] += tmp1;
        bs[t] += tmp2;
        __syncthreads();
    }
    int blockExcl = (blockIdx.x > 0) ? bs[blockIdx.x - 1] : 0;
    int excl = blockExcl + ((t > 0) ? s[t - 1] : 0);
    if (i < N_NODES) row_ptr[i] = excl;
    if (i == 0) row_ptr[N_NODES] = N_EDGES;
}

// ---------- K4: rank-based CSR fill ----------
__global__ void fill_kernel(const int* __restrict__ srcv, const int* __restrict__ dstv,
                            const ushort* __restrict__ rank, const int* __restrict__ row_ptr,
                            ushort* __restrict__ csr_src) {
    int e = blockIdx.x * 256 + threadIdx.x;
    if (e < N_EDGES) {
        int d = dstv[e];
        int pos = row_ptr[d] + (int)rank[e];
        csr_src[pos] = (ushort)srcv[e];
    }
}

// ---------- fused gather(+ELU) then next-layer linYZ through LDS ----------
// PACKED-UNION gather: wave's 4 nodes are CSR-contiguous -> one range [rp0, rp4),
// T ~ 64 edges. 16-edge batches: group g loads edge 4j+g's 128B row (unconditional,
// coalesced, up to 16 loads hoisted in flight); node membership via 0/1 mask fmaf
// (m_n = rp[n] <= e < rp[n+1]). Inflation 1.92x -> ~1.12x vs per-node lockstep.
template <bool FUSE_PROJ>
__global__ void gather_lin_kernel(const ushort* __restrict__ Y, const ushort* __restrict__ Zb,
                                  const float* __restrict__ bl,
                                  const int* __restrict__ row_ptr, const ushort* __restrict__ csr_src,
                                  const ushort* __restrict__ fragWl, const ushort* __restrict__ fragWr,
                                  ushort* __restrict__ Ynext, ushort* __restrict__ Zbnext,
                                  const float* __restrict__ Wp, const float* __restrict__ bp,
                                  float* __restrict__ ps, float* __restrict__ pd) {
    __shared__ ushort Hs[16][72];
    int w = threadIdx.x >> 6;
    int lane = threadIdx.x & 63;
    int wv = (blockIdx.x << 2) + w;
    int n0 = wv << 2;
    int g = lane >> 4;
    int l = lane & 15;

    int rp[5];
#pragma unroll
    for (int i = 0; i < 5; ++i) rp[i] = row_ptr[n0 + i];
    int deg[4];
#pragma unroll
    for (int n = 0; n < 4; ++n) deg[n] = rp[n + 1] - rp[n];
    int E0 = rp[0];
    int T = rp[4] - E0;

    float acc[4][4] = {{0.f}};
    const uint2* __restrict__ Y2 = reinterpret_cast<const uint2*>(Y);

    for (int base = 0; base < T; base += 64) {
        int idx = (int)csr_src[E0 + base + lane];      // contiguous union chunk (padded OK)
        int rem = T - base;
        int nb = (rem + 15) >> 4; if (nb > 4) nb = 4;  // 16-edge batches in this chunk

        uint2 rr[16];
        // ---- loads first: up to 16 unconditional coalesced row-chunk loads in flight ----
#pragma unroll
        for (int b = 0; b < 4; ++b) {
            if (b < nb) {   // wave-uniform
#pragma unroll
                for (int j = 0; j < 4; ++j) {
                    int s = __shfl(idx, b * 16 + 4 * j + g);
                    rr[b * 4 + j] = Y2[s * 16 + l];
                }
            }
        }
        // ---- masked accumulate ----
#pragma unroll
        for (int b = 0; b < 4; ++b) {
            if (b < nb) {   // wave-uniform
#pragma unroll
                for (int j = 0; j < 4; ++j) {
                    int e = E0 + base + b * 16 + 4 * j + g;
                    uint2 v = rr[b * 4 + j];
                    float f0 = bf16_lo(v.x), f1 = bf16_hi(v.x);
                    float f2 = bf16_lo(v.y), f3 = bf16_hi(v.y);
#pragma unroll
                    for (int n = 0; n < 4; ++n) {
                        float m = (e >= rp[n] && e < rp[n + 1]) ? 1.0f : 0.0f;
                        acc[n][0] = fmaf(m, f0, acc[n][0]);
                        acc[n][1] = fmaf(m, f1, acc[n][1]);
                        acc[n][2] = fmaf(m, f2, acc[n][2]);
                        acc[n][3] = fmaf(m, f3, acc[n][3]);
                    }
                }
            }
        }
    }

    // hoist epilogue operand loads before the reduction (overlap latency)
    int node = n0 + g;
    float4 bv = reinterpret_cast<const float4*>(bl)[l];
    uint2 zr = reinterpret_cast<const uint2*>(Zb)[node * 16 + l];

#pragma unroll
    for (int n = 0; n < 4; ++n)
#pragma unroll
        for (int f = 0; f < 4; ++f) {
            acc[n][f] += __shfl_xor(acc[n][f], 16);
            acc[n][f] += __shfl_xor(acc[n][f], 32);
        }

    // epilogue: group g owns node n0+g
    float dgf = (g == 0) ? (float)deg[0] : (g == 1) ? (float)deg[1]
              : (g == 2) ? (float)deg[2] : (float)deg[3];
    float c0 = (g == 0) ? acc[0][0] : (g == 1) ? acc[1][0] : (g == 2) ? acc[2][0] : acc[3][0];
    float c1 = (g == 0) ? acc[0][1] : (g == 1) ? acc[1][1] : (g == 2) ? acc[2][1] : acc[3][1];
    float c2 = (g == 0) ? acc[0][2] : (g == 1) ? acc[1][2] : (g == 2) ? acc[2][2] : acc[3][2];
    float c3 = (g == 0) ? acc[0][3] : (g == 1) ? acc[1][3] : (g == 2) ? acc[2][3] : acc[3][3];
    float inv = 1.0f / fmaxf(dgf, 1.0f);
    float v0 = c0 * inv + bv.x + bf16_lo(zr.x);
    float v1 = c1 * inv + bv.y + bf16_hi(zr.x);
    float v2 = c2 * inv + bv.z + bf16_lo(zr.y);
    float v3 = c3 * inv + bv.w + bf16_hi(zr.y);
    float o0 = v0 > 0.f ? v0 : expm1f(v0);
    float o1 = v1 > 0.f ? v1 : expm1f(v1);
    float o2 = v2 > 0.f ? v2 : expm1f(v2);
    float o3 = v3 > 0.f ? v3 : expm1f(v3);

    if constexpr (FUSE_PROJ) {
        float p0 = 0.f, p1 = 0.f, p2 = 0.f, p3 = 0.f;
        float q0 = 0.f, q1 = 0.f, q2 = 0.f, q3 = 0.f;
        float ov[4] = {o0, o1, o2, o3};
#pragma unroll
        for (int j = 0; j < 4; ++j) {
            int k = 4 * l + j;
            float4 wt = reinterpret_cast<const float4*>(Wp)[k];
            float4 wb = reinterpret_cast<const float4*>(Wp)[D_H + k];
            p0 += ov[j] * wt.x; p1 += ov[j] * wt.y; p2 += ov[j] * wt.z; p3 += ov[j] * wt.w;
            q0 += ov[j] * wb.x; q1 += ov[j] * wb.y; q2 += ov[j] * wb.z; q3 += ov[j] * wb.w;
        }
#pragma unroll
        for (int off = 1; off < 16; off <<= 1) {
            p0 += __shfl_xor(p0, off); p1 += __shfl_xor(p1, off);
            p2 += __shfl_xor(p2, off); p3 += __shfl_xor(p3, off);
            q0 += __shfl_xor(q0, off); q1 += __shfl_xor(q1, off);
            q2 += __shfl_xor(q2, off); q3 += __shfl_xor(q3, off);
        }
        if (l == 0) {
            float4 bpv = *reinterpret_cast<const float4*>(bp);
            float4 pv; pv.x = p0 + bpv.x; pv.y = p1 + bpv.y; pv.z = p2 + bpv.z; pv.w = p3 + bpv.w;
            float4 qv; qv.x = q0; qv.y = q1; qv.z = q2; qv.w = q3;
            reinterpret_cast<float4*>(ps)[node] = pv;   // bp folded into ps
            reinterpret_cast<float4*>(pd)[node] = qv;
        }
    } else {
        ushort4 ob;
        ob.x = f2bf(o0); ob.y = f2bf(o1); ob.z = f2bf(o2); ob.w = f2bf(o3);
        int localrow = w * 4 + g;
        *reinterpret_cast<ushort4*>(&Hs[localrow][4 * l]) = ob;
        __syncthreads();

        int col = lane & 15;
        int quad = lane >> 4;
        bf16x8 blf0 = __builtin_bit_cast(bf16x8,
            *reinterpret_cast<const uint4*>(fragWl + (size_t)((0 * 4 + w) * 64 + lane) * 8));
        bf16x8 blf1 = __builtin_bit_cast(bf16x8,
            *reinterpret_cast<const uint4*>(fragWl + (size_t)((1 * 4 + w) * 64 + lane) * 8));
        bf16x8 brf0 = __builtin_bit_cast(bf16x8,
            *reinterpret_cast<const uint4*>(fragWr + (size_t)((0 * 4 + w) * 64 + lane) * 8));
        bf16x8 brf1 = __builtin_bit_cast(bf16x8,
            *reinterpret_cast<const uint4*>(fragWr + (size_t)((1 * 4 + w) * 64 + lane) * 8));
        bf16x8 a0 = __builtin_bit_cast(bf16x8,
            *reinterpret_cast<const uint4*>(&Hs[col][quad * 8]));
        bf16x8 a1 = __builtin_bit_cast(bf16x8,
            *reinterpret_cast<const uint4*>(&Hs[col][32 + quad * 8]));
        f32x4 accl = {0.f,0.f,0.f,0.f};
        f32x4 accr = {0.f,0.f,0.f,0.f};
        accl = __builtin_amdgcn_mfma_f32_16x16x32_bf16(a0, blf0, accl, 0, 0, 0);
        accl = __builtin_amdgcn_mfma_f32_16x16x32_bf16(a1, blf1, accl, 0, 0, 0);
        accr = __builtin_amdgcn_mfma_f32_16x16x32_bf16(a0, brf0, accr, 0, 0, 0);
        accr = __builtin_amdgcn_mfma_f32_16x16x32_bf16(a1, brf1, accr, 0, 0, 0);

        int n0base = blockIdx.x * 16;
#pragma unroll
        for (int reg = 0; reg < 4; ++reg) {
            size_t r = (size_t)(n0base + quad * 4 + reg) * D_H + w * 16 + col;
            Ynext[r]  = f2bf(accl[reg]);
            Zbnext[r] = f2bf(accr[reg]);
        }
    }
}

__global__ void edge_final_kernel(const int* __restrict__ srcv, const int* __restrict__ dstv,
                                  const float* __restrict__ ps, const float* __restrict__ pd,
                                  float* __restrict__ out) {
    int e = blockIdx.x * 256 + threadIdx.x;
    if (e >= N_EDGES) return;
    float4 a = reinterpret_cast<const float4*>(ps)[srcv[e]];  // already has +bp
    float4 b = reinterpret_cast<const float4*>(pd)[dstv[e]];
    float4 o;
    o.x = a.x + b.x;
    o.y = a.y + b.y;
    o.z = a.z + b.z;
    o.w = a.w + b.w;
    reinterpret_cast<float4*>(out)[e] = o;
}

extern "C" void kernel_launch(void* const* d_in, const int* in_sizes, int n_in,
                              void* d_out, int out_size, void* d_ws, size_t ws_size,
                              hipStream_t stream) {
    const float* x   = (const float*)d_in[0];
    const int*   ei  = (const int*)d_in[1];
    const float* Wl1 = (const float*)d_in[2];
    const float* bl1 = (const float*)d_in[3];
    const float* Wr1 = (const float*)d_in[4];
    const float* Wl2 = (const float*)d_in[5];
    const float* bl2 = (const float*)d_in[6];
    const float* Wr2 = (const float*)d_in[7];
    const float* Wl3 = (const float*)d_in[8];
    const float* bl3 = (const float*)d_in[9];
    const float* Wr3 = (const float*)d_in[10];
    const float* Wp  = (const float*)d_in[11];
    const float* bp  = (const float*)d_in[12];
    float* out = (float*)d_out;

    const int* srcv = ei;
    const int* dstv = ei + N_EDGES;

    // ---- workspace carve-up ----
    int*   cnt       = (int*)d_ws;                     // 50000
    int*   blockSums = cnt + 50000;                    // 256
    int*   row_ptr   = blockSums + 256;                // 50001
    ushort* rank     = (ushort*)(row_ptr + 50001);     // 800000
    ushort* csr_src  = rank + 800000;                  // 800000 (+4096 pad)
    ushort* wfrag = (ushort*)(((uintptr_t)(csr_src + 800000 + 4096) + 127) & ~(uintptr_t)127);
    ushort* Y1  = (ushort*)(((uintptr_t)(wfrag + FRAG_TOTAL) + 127) & ~(uintptr_t)127);
    ushort* Zb1 = Y1 + (size_t)N_NODES * D_H;
    ushort* Y2  = Zb1 + (size_t)N_NODES * D_H;
    ushort* Zb2 = Y2 + (size_t)N_NODES * D_H;
    float* ps = (float*)(((uintptr_t)(Zb2 + (size_t)N_NODES * D_H) + 15) & ~(uintptr_t)15);
    float* pd = ps + (size_t)N_NODES * 4;

    // ---- K1: lin1 (staged 16KB LDS frags) || frag build W2/W3 || hist+rank ----
    hipMemsetAsync(cnt, 0, N_NODES * sizeof(int), stream);
    k1_kernel<<<LIN1_BLOCKS + FRAG_BLOCKS + HIST_BLOCKS, 256, 0, stream>>>(
        x, Wl1, Wr1, Wl2, Wr2, Wl3, Wr3, dstv, cnt, rank, wfrag, Y1, Zb1);

    // ---- K2/K3: two-dispatch scan ----
    scan_partial<<<SCAN_BLOCKS, 256, 0, stream>>>(cnt, blockSums);
    scan_final<<<SCAN_BLOCKS, 256, 0, stream>>>(cnt, blockSums, row_ptr);

    // ---- K4: CSR fill ----
    fill_kernel<<<HIST_BLOCKS, 256, 0, stream>>>(srcv, dstv, rank, row_ptr, csr_src);

    // ---- K5: gather L1 + lin L2 ----
    gather_lin_kernel<false><<<GL_BLOCKS, 256, 0, stream>>>(Y1, Zb1, bl1, row_ptr, csr_src,
                                                            wfrag + F2L, wfrag + F2R, Y2, Zb2,
                                                            nullptr, nullptr, nullptr, nullptr);

    // ---- K6: gather L2 + lin L3 ----
    gather_lin_kernel<false><<<GL_BLOCKS, 256, 0, stream>>>(Y2, Zb2, bl2, row_ptr, csr_src,
                                                            wfrag + F3L, wfrag + F3R, Y1, Zb1,
                                                            nullptr, nullptr, nullptr, nullptr);

    // ---- K7: gather L3 + fused output projection (bp folded into ps) ----
    gather_lin_kernel<true><<<GL_BLOCKS, 256, 0, stream>>>(Y1, Zb1, bl3, row_ptr, csr_src,
                                                           nullptr, nullptr, nullptr, nullptr,
                                                           Wp, bp, ps, pd);

    // ---- K8: edge output ----
    edge_final_kernel<<<(N_EDGES + 255) / 256, 256, 0, stream>>>(srcv, dstv, ps, pd, out);
}